// Round 8
// baseline (143.854 us; speedup 1.0000x reference)
//
#include <hip/hip_runtime.h>
#include <math.h>

namespace {

typedef __bf16 bf16_t;
typedef __bf16 bf16x4 __attribute__((ext_vector_type(4)));
typedef __bf16 bf16x8 __attribute__((ext_vector_type(8)));
typedef float  f32x4  __attribute__((ext_vector_type(4)));

constexpr int kB = 8;
constexpr int kT = 2048;
constexpr int kC = 1024;
constexpr int kH = 64;
constexpr int LDK = 72;   // padded LDS row stride (bf16) for ps (normal ds_write)
constexpr int kSplit = 4;

__device__ inline bf16x8 pack8v(const f32x4 a, const f32x4 b) {
    bf16x8 r;
    r[0] = (bf16_t)a[0]; r[1] = (bf16_t)a[1]; r[2] = (bf16_t)a[2]; r[3] = (bf16_t)a[3];
    r[4] = (bf16_t)b[0]; r[5] = (bf16_t)b[1]; r[6] = (bf16_t)b[2]; r[7] = (bf16_t)b[3];
    return r;
}

// async 16B global->LDS DMA. HW constraint (m104/m108): LDS dst must be
// wave-uniform base + lane*16 — every mapping below satisfies this.
__device__ inline void dma16(const void* g, void* l) {
    __builtin_amdgcn_global_load_lds(
        (const __attribute__((address_space(1))) void*)g,
        (__attribute__((address_space(3))) void*)l, 16, 0, 0);
}

// ---------------------------------------------------------------------------
// Preconvert: wsT[3][64][1024] bf16 = {Wk,Wq,Wv}^T, Wq pre-scaled by H^-0.5.
// ---------------------------------------------------------------------------
__global__ __launch_bounds__(256) void wt_kernel(
    const float* __restrict__ Wk, const float* __restrict__ Wq,
    const float* __restrict__ Wv, bf16_t* __restrict__ wsT)
{
    const int g = blockIdx.x * 256 + threadIdx.x;
    const int wsel = g >> 16;
    const int rem  = g & 65535;
    const int h = rem >> 10, c = rem & 1023;
    const float* W = (wsel == 0) ? Wk : (wsel == 1) ? Wq : Wv;
    float v = W[c * kH + h];
    if (wsel == 1) v *= 0.125f;
    wsT[g] = (bf16_t)v;
}

// ---------------------------------------------------------------------------
// QKV projection. 512 blocks x 256 thr; block = 32 rows of x, K-chunks of 64.
// ALL staging via DMA (W bf16 24 KB + x fp32 8 KB per chunk), double-buffered
// XOR-swizzled LDS, ONE barrier per chunk, DMA issued a full chunk ahead.
// r7 bug fixed: x DMA LDS dst now has lane stride exactly 16
// (f = (w*2+j)*1024 + lane*16), per the wave-uniform-base HW rule.
// ---------------------------------------------------------------------------
__global__ __launch_bounds__(256) void qkv_kernel(
    const float* __restrict__ x, const bf16_t* __restrict__ wsT,
    bf16_t* __restrict__ ko, bf16_t* __restrict__ qo, bf16_t* __restrict__ vT)
{
    __shared__ bf16_t ws[2][12288];   // 2 x 24 KB: 192 rows x 128B, XOR-swizzled
    __shared__ float  xsf[2][2048];   // 2 x 8 KB:   32 rows x 256B, XOR-swizzled

    const int tid = threadIdx.x;
    const int w = tid >> 6, lane = tid & 63;
    const int ml = lane & 15, quad = lane >> 4;
    const long row0 = (long)blockIdx.x * 32;

    // ---- DMA mappings (precomputed; invariant over chunks)
    const char* wbytes = (const char*)wsT;
    const char* xbytes = (const char*)x;
    int wfo[6]; long wso[6];
    #pragma unroll
    for (int j = 0; j < 6; ++j) {
        const int f = (w * 6 + j) * 1024 + lane * 16;   // 0..24575, lane stride 16
        const int i = f >> 7;                            // W row 0..191
        const int cl = (f >> 4) & 7;
        wfo[j] = f;
        wso[j] = (long)i * 2048 + ((cl ^ (i & 7)) << 4); // + it*128
    }
    int xfo[2]; long xso[2];
    #pragma unroll
    for (int j = 0; j < 2; ++j) {
        const int f = (w * 2 + j) * 1024 + lane * 16;    // 0..8191, lane stride 16
        const int i = f >> 8;                            // x row 0..31
        const int cl = (f >> 4) & 15;
        xfo[j] = f;
        xso[j] = (row0 + i) * 4096 + ((cl ^ (i & 7)) << 4); // + it*256
    }

    int wsel[3], ntv[3];
    #pragma unroll
    for (int j = 0; j < 3; ++j) {
        const int pi = 3 * w + j;
        wsel[j] = pi >> 2; ntv[j] = pi & 3;
    }

    f32x4 acc[3][2];
    #pragma unroll
    for (int j = 0; j < 3; ++j)
        #pragma unroll
        for (int mt = 0; mt < 2; ++mt)
            #pragma unroll
            for (int r = 0; r < 4; ++r) acc[j][mt][r] = 0.f;

    // ---- prologue: chunk 0 -> buf 0
    #pragma unroll
    for (int j = 0; j < 6; ++j) dma16(wbytes + wso[j], (char*)ws[0] + wfo[j]);
    #pragma unroll
    for (int j = 0; j < 2; ++j) dma16(xbytes + xso[j], (char*)xsf[0] + xfo[j]);
    __syncthreads();

    for (int it = 0; it < 16; ++it) {
        const int buf = it & 1;
        if (it < 15) {   // issue chunk it+1 into buf^1; drains at end-of-iter barrier
            #pragma unroll
            for (int j = 0; j < 6; ++j)
                dma16(wbytes + wso[j] + (long)(it + 1) * 128, (char*)ws[buf ^ 1] + wfo[j]);
            #pragma unroll
            for (int j = 0; j < 2; ++j)
                dma16(xbytes + xso[j] + (long)(it + 1) * 256, (char*)xsf[buf ^ 1] + xfo[j]);
        }

        // A-frags: fp32 LDS -> bf16 (rows mt*16+ml; k = h2*32+quad*8..+7)
        bf16x8 a[2][2];
        #pragma unroll
        for (int mt = 0; mt < 2; ++mt)
            #pragma unroll
            for (int h2 = 0; h2 < 2; ++h2) {
                const int rr = mt * 16 + ml;
                const int c = h2 * 8 + quad * 2;
                const f32x4 u0 = *(const f32x4*)((const char*)xsf[buf] + rr * 256 +
                                     (((c    ) ^ (ml & 7)) << 4));
                const f32x4 u1 = *(const f32x4*)((const char*)xsf[buf] + rr * 256 +
                                     (((c + 1) ^ (ml & 7)) << 4));
                a[mt][h2] = pack8v(u0, u1);
            }

        #pragma unroll
        for (int j = 0; j < 3; ++j) {
            const int row = wsel[j] * 64 + ntv[j] * 16 + ml;
            #pragma unroll
            for (int h2 = 0; h2 < 2; ++h2) {
                const bf16x8 bfr = *(const bf16x8*)((const char*)ws[buf] + row * 128 +
                                       (((h2 * 4 + quad) ^ (ml & 7)) << 4));
                #pragma unroll
                for (int mt = 0; mt < 2; ++mt)
                    acc[j][mt] = __builtin_amdgcn_mfma_f32_16x16x32_bf16(
                        a[mt][h2], bfr, acc[j][mt], 0, 0, 0);
            }
        }
        __syncthreads();   // drains DMA(it+1) + protects both buffers
    }

    const int bb  = (int)(row0 >> 11);
    const int tb0 = (int)(row0 & (kT - 1));
    #pragma unroll
    for (int j = 0; j < 3; ++j) {
        const int h = ntv[j] * 16 + ml;
        #pragma unroll
        for (int mt = 0; mt < 2; ++mt) {
            if (wsel[j] == 2) {   // v -> transposed [b][h][t]
                bf16x4 pv;
                #pragma unroll
                for (int r = 0; r < 4; ++r) pv[r] = (bf16_t)acc[j][mt][r];
                *(bf16x4*)&vT[((long)(bb * kH + h)) * kT + tb0 + mt * 16 + quad * 4] = pv;
            } else {
                bf16_t* dst = (wsel[j] == 0) ? ko : qo;
                #pragma unroll
                for (int r = 0; r < 4; ++r)
                    dst[(row0 + mt * 16 + quad * 4 + r) * kH + h] = (bf16_t)acc[j][mt][r];
            }
        }
    }
}

// ---------------------------------------------------------------------------
// Attention pass 1: split-s flash, S^T formulation, double-buffered DMA K/V
// tiles, ONE barrier per s-tile (DMA issued a full tile ahead).
// Grid = B * 32(qt of 64 rows) * kSplit, 256 thr (4 waves).
// ---------------------------------------------------------------------------
__global__ __launch_bounds__(256) void attn1_kernel(
    const bf16_t* __restrict__ qg, const bf16_t* __restrict__ kg,
    const bf16_t* __restrict__ vT, float* __restrict__ Opart,
    float* __restrict__ mbuf, float* __restrict__ lbuf)
{
    __shared__ bf16_t ks[2][4096];   // 2 x 8 KB, 64 rows x 128B, XOR swizzle
    __shared__ bf16_t vs[2][4096];
    __shared__ bf16_t ps[64][LDK];   // P, padded, wave-private 16-row slices

    const int tid = threadIdx.x;
    const int w = tid >> 6, lane = tid & 63;
    const int ml = lane & 15, quad = lane >> 4;
    const int bx = blockIdx.x;
    const int sp  = bx & 3;
    const int qti = (bx >> 2) & 31;
    const int b   = bx >> 7;
    const int u   = qti >> 1;
    const int qt  = (qti & 1) ? (31 - u) : u;   // complementary pairing
    const int p   = (b * 32 + qt) * kSplit + sp;
    float* op = Opart + (long)p * 4096;         // [64][64]

    if (sp > qt) {                               // empty split: sentinels
        const int zr = tid >> 2, zc = (tid & 3) * 16;
        const float4 z = make_float4(0.f, 0.f, 0.f, 0.f);
        #pragma unroll
        for (int j = 0; j < 4; ++j) *(float4*)&op[zr * 64 + zc + j * 4] = z;
        if (tid < 64) {
            mbuf[p * 64 + tid] = -INFINITY;
            lbuf[p * 64 + tid] = 0.f;
        }
        return;                                  // block-uniform exit, no barriers
    }

    // Q B-frags (Q pre-scaled by 0.125): lane ml = t-row qt*64 + w*16 + ml
    const long qoff = ((long)b * kT + qt * 64 + w * 16 + ml) * kH + quad * 8;
    const bf16x8 bq0 = *(const bf16x8*)&qg[qoff];
    const bf16x8 bq1 = *(const bf16x8*)&qg[qoff + 32];

    // DMA mapping: 2 rounds K + 2 rounds V per thread (16 KB per tile),
    // LDS dst lane stride exactly 16
    const char* kbase = (const char*)kg + (long)b * kT * kH * 2;
    const char* vbase = (const char*)vT + (long)b * kH * kT * 2;
    int fo[2]; long kso[2], vso[2];
    #pragma unroll
    for (int j = 0; j < 2; ++j) {
        const int f = w * 2048 + j * 1024 + lane * 16;
        const int i = f >> 7;                    // row 0..63
        const int cl = (f >> 4) & 7;
        const int c = (cl ^ (i & 7)) << 4;
        fo[j]  = f;
        kso[j] = (long)i * 128 + c;              // + st*8192
        vso[j] = (long)i * 4096 + c;             // + st*128
    }

    f32x4 o[4];
    #pragma unroll
    for (int nt = 0; nt < 4; ++nt)
        #pragma unroll
        for (int r = 0; r < 4; ++r) o[nt][r] = 0.f;
    float m = -INFINITY, l = 0.f;

    // prologue: tile sp -> buf 0
    #pragma unroll
    for (int j = 0; j < 2; ++j) {
        dma16(kbase + (long)sp * 8192 + kso[j], (char*)ks[0] + fo[j]);
        dma16(vbase + (long)sp * 128  + vso[j], (char*)vs[0] + fo[j]);
    }
    __syncthreads();

    int buf = 0;
    for (int st = sp; st <= qt; st += kSplit) {
        if (st + kSplit <= qt) {   // issue next tile into buf^1
            #pragma unroll
            for (int j = 0; j < 2; ++j) {
                dma16(kbase + (long)(st + kSplit) * 8192 + kso[j], (char*)ks[buf ^ 1] + fo[j]);
                dma16(vbase + (long)(st + kSplit) * 128  + vso[j], (char*)vs[buf ^ 1] + fo[j]);
            }
        }

        // S^T = K Q^T : rows s = st*64+nt*16+quad*4+r, cols t (lane ml)
        f32x4 s[4];
        #pragma unroll
        for (int nt = 0; nt < 4; ++nt)
            #pragma unroll
            for (int r = 0; r < 4; ++r) s[nt][r] = 0.f;
        #pragma unroll
        for (int nt = 0; nt < 4; ++nt) {
            const int row = (nt * 16 + ml) * 128;
            #pragma unroll
            for (int h2 = 0; h2 < 2; ++h2) {
                const bf16x8 kf = *(const bf16x8*)((const char*)ks[buf] + row +
                                      (((h2 * 4 + quad) ^ (ml & 7)) << 4));
                s[nt] = __builtin_amdgcn_mfma_f32_16x16x32_bf16(
                    kf, (h2 == 0) ? bq0 : bq1, s[nt], 0, 0, 0);
            }
        }

        if (st == qt) {   // diagonal tile: mask s-local > t-local
            const int tl = w * 16 + ml;
            #pragma unroll
            for (int nt = 0; nt < 4; ++nt)
                #pragma unroll
                for (int r = 0; r < 4; ++r)
                    if (nt * 16 + quad * 4 + r > tl) s[nt][r] = -INFINITY;
        }

        // online softmax, per-lane row (16 in-lane values + shfl 16,32)
        float mx = -INFINITY;
        #pragma unroll
        for (int nt = 0; nt < 4; ++nt)
            #pragma unroll
            for (int r = 0; r < 4; ++r) mx = fmaxf(mx, s[nt][r]);
        mx = fmaxf(mx, __shfl_xor(mx, 16));
        mx = fmaxf(mx, __shfl_xor(mx, 32));
        const float mnew  = fmaxf(m, mx);
        const float alpha = __expf(m - mnew);
        m = mnew;
        float psum = 0.f, pr[4][4];
        #pragma unroll
        for (int nt = 0; nt < 4; ++nt)
            #pragma unroll
            for (int r = 0; r < 4; ++r) {
                pr[nt][r] = __expf(s[nt][r] - mnew);
                psum += pr[nt][r];
            }
        psum += __shfl_xor(psum, 16);
        psum += __shfl_xor(psum, 32);
        l = l * alpha + psum;
        #pragma unroll
        for (int nt = 0; nt < 4; ++nt)
            #pragma unroll
            for (int r = 0; r < 4; ++r) o[nt][r] *= alpha;

        // P -> wave-private LDS rows, packed b64
        #pragma unroll
        for (int nt = 0; nt < 4; ++nt) {
            bf16x4 pk;
            #pragma unroll
            for (int r = 0; r < 4; ++r) pk[r] = (bf16_t)pr[nt][r];
            *(bf16x4*)&ps[w * 16 + ml][nt * 16 + quad * 4] = pk;
        }
        const bf16x8 pf0 = *(const bf16x8*)&ps[w * 16 + ml][quad * 8];
        const bf16x8 pf1 = *(const bf16x8*)&ps[w * 16 + ml][32 + quad * 8];

        // O^T += V^T P^T
        #pragma unroll
        for (int nt = 0; nt < 4; ++nt) {
            const int row = (nt * 16 + ml) * 128;
            #pragma unroll
            for (int kc2 = 0; kc2 < 2; ++kc2) {
                const bf16x8 vf = *(const bf16x8*)((const char*)vs[buf] + row +
                                      (((kc2 * 4 + quad) ^ (ml & 7)) << 4));
                o[nt] = __builtin_amdgcn_mfma_f32_16x16x32_bf16(
                    vf, (kc2 == 0) ? pf0 : pf1, o[nt], 0, 0, 0);
            }
        }
        __syncthreads();   // drains next-tile DMA + protects buffers
        buf ^= 1;
    }

    #pragma unroll
    for (int nt = 0; nt < 4; ++nt)
        *(f32x4*)&op[(w * 16 + ml) * 64 + nt * 16 + quad * 4] = o[nt];
    if (quad == 0) {
        mbuf[p * 64 + w * 16 + ml] = m;
        lbuf[p * 64 + w * 16 + ml] = l;
    }
}

// ---------------------------------------------------------------------------
// Attention pass 2: combine kSplit partials per row. 1024 blocks x 256 thr.
// ---------------------------------------------------------------------------
__global__ __launch_bounds__(256) void attn2_kernel(
    const float* __restrict__ Opart, const float* __restrict__ mbuf,
    const float* __restrict__ lbuf, float* __restrict__ outg)
{
    const int g = blockIdx.x * 256 + threadIdx.x;   // 0 .. 262143
    const int h4  = (g & 15) * 4;
    const int row = (g >> 4) & 63;
    const int qt  = (g >> 10) & 31;
    const int b   = g >> 15;
    const int p0  = (b * 32 + qt) * kSplit;

    float mm[kSplit];
    float M = -INFINITY;
    #pragma unroll
    for (int sp = 0; sp < kSplit; ++sp) {
        mm[sp] = mbuf[(p0 + sp) * 64 + row];
        M = fmaxf(M, mm[sp]);
    }
    float4 acc = make_float4(0.f, 0.f, 0.f, 0.f);
    float lt = 0.f;
    #pragma unroll
    for (int sp = 0; sp < kSplit; ++sp) {
        const float wgt = __expf(mm[sp] - M);
        lt += wgt * lbuf[(p0 + sp) * 64 + row];
        const float4 ov = *(const float4*)&Opart[(long)(p0 + sp) * 4096 + row * 64 + h4];
        acc.x += wgt * ov.x; acc.y += wgt * ov.y;
        acc.z += wgt * ov.z; acc.w += wgt * ov.w;
    }
    const float inv = 1.0f / lt;
    acc.x *= inv; acc.y *= inv; acc.z *= inv; acc.w *= inv;
    *(float4*)&outg[(((long)(b * 32 + qt) * 64 + row)) * 64 + h4] = acc;
}

} // anonymous namespace

extern "C" void kernel_launch(void* const* d_in, const int* in_sizes, int n_in,
                              void* d_out, int out_size, void* d_ws, size_t ws_size,
                              hipStream_t stream) {
    (void)in_sizes; (void)n_in; (void)out_size; (void)ws_size;
    const float* x  = (const float*)d_in[0];
    const float* Wk = (const float*)d_in[1];
    const float* Wq = (const float*)d_in[2];
    const float* Wv = (const float*)d_in[3];
    float* out = (float*)d_out;

    const size_t N = (size_t)kB * kT * kH;           // 1M elements
    bf16_t* wsT = (bf16_t*)d_ws;                     // 3*64*1024 bf16
    bf16_t* k   = wsT + (size_t)3 * kH * kC;
    bf16_t* q   = k + N;
    bf16_t* vT  = q + N;
    float* Opart = (float*)(vT + N);                 // [8*32*kSplit][64][64] fp32
    float* mbuf  = Opart + (size_t)kB * 32 * kSplit * 4096;
    float* lbuf  = mbuf + (size_t)kB * 32 * kSplit * 64;

    wt_kernel<<<(3 * kH * kC) / 256, 256, 0, stream>>>(Wk, Wq, Wv, wsT);
    qkv_kernel<<<(kB * kT) / 32, 256, 0, stream>>>(x, wsT, k, q, vT);
    attn1_kernel<<<kB * 32 * kSplit, 256, 0, stream>>>(q, k, vT, Opart, mbuf, lbuf);
    attn2_kernel<<<(kB * kT * kH / 4) / 256, 256, 0, stream>>>(Opart, mbuf, lbuf, out);
}

// Round 9
// 132.146 us; speedup vs baseline: 1.0886x; 1.0886x over previous
//
#include <hip/hip_runtime.h>
#include <math.h>

namespace {

typedef __bf16 bf16_t;
typedef __bf16 bf16x4 __attribute__((ext_vector_type(4)));
typedef __bf16 bf16x8 __attribute__((ext_vector_type(8)));
typedef float  f32x4  __attribute__((ext_vector_type(4)));

constexpr int kB = 8;
constexpr int kT = 2048;
constexpr int kC = 1024;
constexpr int kH = 64;
constexpr int LDK = 72;   // padded LDS row stride (bf16) for ps/xs (normal ds_write)
constexpr int kSplit = 4;

__device__ inline bf16x8 pack8(const float4 a, const float4 b) {
    bf16x8 r;
    r[0] = (bf16_t)a.x; r[1] = (bf16_t)a.y; r[2] = (bf16_t)a.z; r[3] = (bf16_t)a.w;
    r[4] = (bf16_t)b.x; r[5] = (bf16_t)b.y; r[6] = (bf16_t)b.z; r[7] = (bf16_t)b.w;
    return r;
}

// async 16B global->LDS DMA. HW rule (m104/m108): LDS dst = wave-uniform base
// + lane*16 — all mappings below satisfy this.
__device__ inline void dma16(const void* g, void* l) {
    __builtin_amdgcn_global_load_lds(
        (const __attribute__((address_space(1))) void*)g,
        (__attribute__((address_space(3))) void*)l, 16, 0, 0);
}

// ---------------------------------------------------------------------------
// Preconvert: wsT[3][64][1024] bf16 = {Wk,Wq,Wv}^T, Wq pre-scaled by H^-0.5.
// ---------------------------------------------------------------------------
__global__ __launch_bounds__(256) void wt_kernel(
    const float* __restrict__ Wk, const float* __restrict__ Wq,
    const float* __restrict__ Wv, bf16_t* __restrict__ wsT)
{
    const int g = blockIdx.x * 256 + threadIdx.x;
    const int wsel = g >> 16;
    const int rem  = g & 65535;
    const int h = rem >> 10, c = rem & 1023;
    const float* W = (wsel == 0) ? Wk : (wsel == 1) ? Wq : Wv;
    float v = W[c * kH + h];
    if (wsel == 1) v *= 0.125f;
    wsT[g] = (bf16_t)v;
}

// ---------------------------------------------------------------------------
// QKV projection — r6 body (best known: ~35 us). 512 blocks x 256 thr;
// block = 32 rows of x, K-chunks of 64. W chunk (24 KB) via DMA into
// XOR-swizzled LDS; x staged via reg prefetch + padded LDS. 2 barriers/chunk.
// ---------------------------------------------------------------------------
__global__ __launch_bounds__(256) void qkv_kernel(
    const float* __restrict__ x, const bf16_t* __restrict__ wsT,
    bf16_t* __restrict__ ko, bf16_t* __restrict__ qo, bf16_t* __restrict__ vT)
{
    __shared__ bf16_t ws[192 * 64];   // 24 KB, rows of 128B, 16B-chunk XOR swizzle
    __shared__ bf16_t xs[32][LDK];    // padded, normal ds_write

    const int tid = threadIdx.x;
    const int w = tid >> 6, lane = tid & 63;
    const int ml = lane & 15, quad = lane >> 4;
    const long row0 = (long)blockIdx.x * 32;

    const int srow = tid >> 3;
    const int scol = (tid & 7) * 8;
    const float* xrow = x + (row0 + srow) * kC + scol;

    const char* wbytes = (const char*)wsT;
    int wfo[6]; long wso[6];
    #pragma unroll
    for (int j = 0; j < 6; ++j) {
        const int f = (w * 6 + j) * 1024 + lane * 16;    // lane stride exactly 16
        const int i = f >> 7;                             // W row 0..191
        const int cl = (f >> 4) & 7;
        wfo[j] = f;
        wso[j] = (long)i * 2048 + ((cl ^ (i & 7)) << 4);  // + it*128
    }

    int wsel[3], ntv[3];
    #pragma unroll
    for (int j = 0; j < 3; ++j) {
        const int pi = 3 * w + j;
        wsel[j] = pi >> 2; ntv[j] = pi & 3;
    }

    f32x4 acc[3][2];
    #pragma unroll
    for (int j = 0; j < 3; ++j)
        #pragma unroll
        for (int mt = 0; mt < 2; ++mt)
            #pragma unroll
            for (int r = 0; r < 4; ++r) acc[j][mt][r] = 0.f;

    float4 xa = *(const float4*)&xrow[0];
    float4 xb = *(const float4*)&xrow[4];

    for (int it = 0; it < 16; ++it) {
        const long c0b = (long)it * 128;           // W byte offset of this K-chunk
        __syncthreads();                            // (a) prev chunk reads done
        *(bf16x8*)&xs[srow][scol] = pack8(xa, xb);
        if (it < 15) {
            xa = *(const float4*)&xrow[(it + 1) * 64];
            xb = *(const float4*)&xrow[(it + 1) * 64 + 4];
        }
        #pragma unroll
        for (int j = 0; j < 6; ++j)
            dma16(wbytes + wso[j] + c0b, (char*)ws + wfo[j]);
        __syncthreads();                            // (b) DMA drained + x visible

        bf16x8 a[2][2];
        #pragma unroll
        for (int mt = 0; mt < 2; ++mt)
            #pragma unroll
            for (int h2 = 0; h2 < 2; ++h2)
                a[mt][h2] = *(const bf16x8*)&xs[mt * 16 + ml][h2 * 32 + quad * 8];

        #pragma unroll
        for (int j = 0; j < 3; ++j) {
            const int row = wsel[j] * 64 + ntv[j] * 16 + ml;
            #pragma unroll
            for (int h2 = 0; h2 < 2; ++h2) {
                const bf16x8 bfr = *(const bf16x8*)((const char*)ws + row * 128 +
                                       (((h2 * 4 + quad) ^ (ml & 7)) << 4));
                #pragma unroll
                for (int mt = 0; mt < 2; ++mt)
                    acc[j][mt] = __builtin_amdgcn_mfma_f32_16x16x32_bf16(
                        a[mt][h2], bfr, acc[j][mt], 0, 0, 0);
            }
        }
    }

    const int bb  = (int)(row0 >> 11);
    const int tb0 = (int)(row0 & (kT - 1));
    #pragma unroll
    for (int j = 0; j < 3; ++j) {
        const int h = ntv[j] * 16 + ml;
        #pragma unroll
        for (int mt = 0; mt < 2; ++mt) {
            if (wsel[j] == 2) {   // v -> transposed [b][h][t]
                bf16x4 pv;
                #pragma unroll
                for (int r = 0; r < 4; ++r) pv[r] = (bf16_t)acc[j][mt][r];
                *(bf16x4*)&vT[((long)(bb * kH + h)) * kT + tb0 + mt * 16 + quad * 4] = pv;
            } else {
                bf16_t* dst = (wsel[j] == 0) ? ko : qo;
                #pragma unroll
                for (int r = 0; r < 4; ++r)
                    dst[(row0 + mt * 16 + quad * 4 + r) * kH + h] = (bf16_t)acc[j][mt][r];
            }
        }
    }
}

// ---------------------------------------------------------------------------
// Attention pass 1 — r6 body + CU-BALANCED bid swizzle.
// Co-resident blocks on a CU are bid, bid+256, bid+512, bid+768 (stride-256).
// Old mapping gave all four the SAME (qt,sp) -> per-CU work ranged 0..32
// tile-iters (heaviest CU set the wall). New mapping: cu=bid&255 carries
// (b,u); rep=bid>>8 carries sp=rep and qt = (rep odd) ? 31-u : u.
// Per-CU tile count is exactly 17 for every CU; coverage is a bijection.
// ---------------------------------------------------------------------------
__global__ __launch_bounds__(256) void attn1_kernel(
    const bf16_t* __restrict__ qg, const bf16_t* __restrict__ kg,
    const bf16_t* __restrict__ vT, float* __restrict__ Opart,
    float* __restrict__ mbuf, float* __restrict__ lbuf)
{
    __shared__ bf16_t ks[4096];      // 64 s-rows x 64 h, 128B rows, XOR swizzle
    __shared__ bf16_t vs[4096];      // 64 h-rows x 64 s, 128B rows, XOR swizzle
    __shared__ bf16_t ps[64][LDK];   // P, padded, wave-private 16-row slices

    const int tid = threadIdx.x;
    const int w = tid >> 6, lane = tid & 63;
    const int ml = lane & 15, quad = lane >> 4;
    const int bx = blockIdx.x;
    const int cu  = bx & 255;                   // stride-256 co-residency class
    const int rep = bx >> 8;                    // 0..3
    const int b   = cu >> 5;
    const int u   = cu & 31;
    const int qt  = (rep & 1) ? (31 - u) : u;   // pair u / 31-u WITHIN the class
    const int sp  = rep;
    const int p   = (b * 32 + qt) * kSplit + sp;
    float* op = Opart + (long)p * 4096;         // [64][64]

    if (sp > qt) {                               // empty split: sentinels
        const int zr = tid >> 2, zc = (tid & 3) * 16;
        const float4 z = make_float4(0.f, 0.f, 0.f, 0.f);
        #pragma unroll
        for (int j = 0; j < 4; ++j) *(float4*)&op[zr * 64 + zc + j * 4] = z;
        if (tid < 64) {
            mbuf[p * 64 + tid] = -INFINITY;
            lbuf[p * 64 + tid] = 0.f;
        }
        return;                                  // block-uniform exit
    }

    // Q B-frags (Q pre-scaled by 0.125): lane ml = t-row qt*64 + w*16 + ml
    const long qoff = ((long)b * kT + qt * 64 + w * 16 + ml) * kH + quad * 8;
    const bf16x8 bq0 = *(const bf16x8*)&qg[qoff];
    const bf16x8 bq1 = *(const bf16x8*)&qg[qoff + 32];

    // DMA mapping: 2 rounds K + 2 rounds V per thread (16 KB per tile)
    const char* kbase = (const char*)kg + (long)b * kT * kH * 2;
    const char* vbase = (const char*)vT + (long)b * kH * kT * 2;
    int fo[2]; long kso[2], vso[2];
    #pragma unroll
    for (int j = 0; j < 2; ++j) {
        const int f = w * 2048 + j * 1024 + lane * 16;
        const int i = f >> 7;                    // row 0..63
        const int cl = (f >> 4) & 7;
        const int c = (cl ^ (i & 7)) << 4;
        fo[j]  = f;
        kso[j] = (long)i * 128 + c;              // + st*8192
        vso[j] = (long)i * 4096 + c;             // + st*128
    }

    f32x4 o[4];
    #pragma unroll
    for (int nt = 0; nt < 4; ++nt)
        #pragma unroll
        for (int r = 0; r < 4; ++r) o[nt][r] = 0.f;
    float m = -INFINITY, l = 0.f;

    for (int st = sp; st <= qt; st += kSplit) {
        __syncthreads();                          // (a) prev tile reads done
        #pragma unroll
        for (int j = 0; j < 2; ++j) {
            dma16(kbase + (long)st * 8192 + kso[j], (char*)ks + fo[j]);
            dma16(vbase + (long)st * 128  + vso[j], (char*)vs + fo[j]);
        }
        __syncthreads();                          // (b) DMA drained, tile ready

        // S^T = K Q^T : rows s = st*64+nt*16+quad*4+r, cols t (lane ml)
        f32x4 s[4];
        #pragma unroll
        for (int nt = 0; nt < 4; ++nt)
            #pragma unroll
            for (int r = 0; r < 4; ++r) s[nt][r] = 0.f;
        #pragma unroll
        for (int nt = 0; nt < 4; ++nt) {
            const int row = (nt * 16 + ml) * 128;
            #pragma unroll
            for (int h2 = 0; h2 < 2; ++h2) {
                const bf16x8 kf = *(const bf16x8*)((const char*)ks + row +
                                      (((h2 * 4 + quad) ^ (ml & 7)) << 4));
                s[nt] = __builtin_amdgcn_mfma_f32_16x16x32_bf16(
                    kf, (h2 == 0) ? bq0 : bq1, s[nt], 0, 0, 0);
            }
        }

        if (st == qt) {   // diagonal tile: mask s-local > t-local
            const int tl = w * 16 + ml;
            #pragma unroll
            for (int nt = 0; nt < 4; ++nt)
                #pragma unroll
                for (int r = 0; r < 4; ++r)
                    if (nt * 16 + quad * 4 + r > tl) s[nt][r] = -INFINITY;
        }

        // online softmax, per-lane row (16 in-lane values + shfl 16,32)
        float mx = -INFINITY;
        #pragma unroll
        for (int nt = 0; nt < 4; ++nt)
            #pragma unroll
            for (int r = 0; r < 4; ++r) mx = fmaxf(mx, s[nt][r]);
        mx = fmaxf(mx, __shfl_xor(mx, 16));
        mx = fmaxf(mx, __shfl_xor(mx, 32));
        const float mnew  = fmaxf(m, mx);
        const float alpha = __expf(m - mnew);
        m = mnew;
        float psum = 0.f, pr[4][4];
        #pragma unroll
        for (int nt = 0; nt < 4; ++nt)
            #pragma unroll
            for (int r = 0; r < 4; ++r) {
                pr[nt][r] = __expf(s[nt][r] - mnew);
                psum += pr[nt][r];
            }
        psum += __shfl_xor(psum, 16);
        psum += __shfl_xor(psum, 32);
        l = l * alpha + psum;
        #pragma unroll
        for (int nt = 0; nt < 4; ++nt)
            #pragma unroll
            for (int r = 0; r < 4; ++r) o[nt][r] *= alpha;

        // P -> wave-private LDS rows, packed b64
        #pragma unroll
        for (int nt = 0; nt < 4; ++nt) {
            bf16x4 pk;
            #pragma unroll
            for (int r = 0; r < 4; ++r) pk[r] = (bf16_t)pr[nt][r];
            *(bf16x4*)&ps[w * 16 + ml][nt * 16 + quad * 4] = pk;
        }
        const bf16x8 pf0 = *(const bf16x8*)&ps[w * 16 + ml][quad * 8];
        const bf16x8 pf1 = *(const bf16x8*)&ps[w * 16 + ml][32 + quad * 8];

        // O^T += V^T P^T
        #pragma unroll
        for (int nt = 0; nt < 4; ++nt) {
            const int row = (nt * 16 + ml) * 128;
            #pragma unroll
            for (int kc2 = 0; kc2 < 2; ++kc2) {
                const bf16x8 vf = *(const bf16x8*)((const char*)vs + row +
                                      (((kc2 * 4 + quad) ^ (ml & 7)) << 4));
                o[nt] = __builtin_amdgcn_mfma_f32_16x16x32_bf16(
                    vf, (kc2 == 0) ? pf0 : pf1, o[nt], 0, 0, 0);
            }
        }
    }

    #pragma unroll
    for (int nt = 0; nt < 4; ++nt)
        *(f32x4*)&op[(w * 16 + ml) * 64 + nt * 16 + quad * 4] = o[nt];
    if (quad == 0) {
        mbuf[p * 64 + w * 16 + ml] = m;
        lbuf[p * 64 + w * 16 + ml] = l;
    }
}

// ---------------------------------------------------------------------------
// Attention pass 2: combine kSplit partials per row. 1024 blocks x 256 thr.
// ---------------------------------------------------------------------------
__global__ __launch_bounds__(256) void attn2_kernel(
    const float* __restrict__ Opart, const float* __restrict__ mbuf,
    const float* __restrict__ lbuf, float* __restrict__ outg)
{
    const int g = blockIdx.x * 256 + threadIdx.x;   // 0 .. 262143
    const int h4  = (g & 15) * 4;
    const int row = (g >> 4) & 63;
    const int qt  = (g >> 10) & 31;
    const int b   = g >> 15;
    const int p0  = (b * 32 + qt) * kSplit;

    float mm[kSplit];
    float M = -INFINITY;
    #pragma unroll
    for (int sp = 0; sp < kSplit; ++sp) {
        mm[sp] = mbuf[(p0 + sp) * 64 + row];
        M = fmaxf(M, mm[sp]);
    }
    float4 acc = make_float4(0.f, 0.f, 0.f, 0.f);
    float lt = 0.f;
    #pragma unroll
    for (int sp = 0; sp < kSplit; ++sp) {
        const float wgt = __expf(mm[sp] - M);
        lt += wgt * lbuf[(p0 + sp) * 64 + row];
        const float4 ov = *(const float4*)&Opart[(long)(p0 + sp) * 4096 + row * 64 + h4];
        acc.x += wgt * ov.x; acc.y += wgt * ov.y;
        acc.z += wgt * ov.z; acc.w += wgt * ov.w;
    }
    const float inv = 1.0f / lt;
    acc.x *= inv; acc.y *= inv; acc.z *= inv; acc.w *= inv;
    *(float4*)&outg[(((long)(b * 32 + qt) * 64 + row)) * 64 + h4] = acc;
}

} // anonymous namespace

extern "C" void kernel_launch(void* const* d_in, const int* in_sizes, int n_in,
                              void* d_out, int out_size, void* d_ws, size_t ws_size,
                              hipStream_t stream) {
    (void)in_sizes; (void)n_in; (void)out_size; (void)ws_size;
    const float* x  = (const float*)d_in[0];
    const float* Wk = (const float*)d_in[1];
    const float* Wq = (const float*)d_in[2];
    const float* Wv = (const float*)d_in[3];
    float* out = (float*)d_out;

    const size_t N = (size_t)kB * kT * kH;           // 1M elements
    bf16_t* wsT = (bf16_t*)d_ws;                     // 3*64*1024 bf16
    bf16_t* k   = wsT + (size_t)3 * kH * kC;
    bf16_t* q   = k + N;
    bf16_t* vT  = q + N;
    float* Opart = (float*)(vT + N);                 // [8*32*kSplit][64][64] fp32
    float* mbuf  = Opart + (size_t)kB * 32 * kSplit * 4096;
    float* lbuf  = mbuf + (size_t)kB * 32 * kSplit * 64;

    wt_kernel<<<(3 * kH * kC) / 256, 256, 0, stream>>>(Wk, Wq, Wv, wsT);
    qkv_kernel<<<(kB * kT) / 32, 256, 0, stream>>>(x, wsT, k, q, vT);
    attn1_kernel<<<kB * 32 * kSplit, 256, 0, stream>>>(q, k, vT, Opart, mbuf, lbuf);
    attn2_kernel<<<(kB * kT * kH / 4) / 256, 256, 0, stream>>>(Opart, mbuf, lbuf, out);
}